// Round 9
// baseline (287.355 us; speedup 1.0000x reference)
//
#include <hip/hip_runtime.h>

// Problem constants (B=1)
constexpr int Cc = 32;
constexpr int Dd = 48;
constexpr int Hh = 96;
constexpr int Ww = 192;
constexpr int TW = 16;           // W-kernel tile width
constexpr int NT = Ww / TW;      // 12 tiles
constexpr float NEGBIG = -3.402823466e+38f;

// ---- DPP helpers ------------------------------------------------------------
// NOTE: must use __builtin_amdgcn_update_dpp (not inline asm) — the compiler's
// hazard recognizer inserts the required VALU->DPP wait states only for
// compiler-known DPP ops. Inline-asm DPP caused silent corruption (round 3).
template <int CTRL, int RM>
__device__ __forceinline__ float dppmov(float v) {
    int i = __builtin_bit_cast(int, v);
    int r = __builtin_amdgcn_update_dpp(i, i, CTRL, RM, 0xF, false);
    return __builtin_bit_cast(float, r);
}

__device__ __forceinline__ float rdlane(float v, int idx) {
    int r = __builtin_amdgcn_readlane(__builtin_bit_cast(int, v), idx);
    return __builtin_bit_cast(float, r);
}

__device__ __forceinline__ unsigned f2h(float v) {
    return (unsigned)__builtin_bit_cast(unsigned short, (_Float16)v);
}
__device__ __forceinline__ float h2f(unsigned short u) {
    return (float)__builtin_bit_cast(_Float16, u);
}

// Max over lanes 0..47, broadcast. Row-confined: junk in lanes 48..63 never
// enters the reduction.
__device__ __forceinline__ float wave_max48(float v) {
    v = fmaxf(v, dppmov<0x111, 0xF>(v));   // row_shr:1
    v = fmaxf(v, dppmov<0x112, 0xF>(v));   // row_shr:2
    v = fmaxf(v, dppmov<0x114, 0xF>(v));   // row_shr:4
    v = fmaxf(v, dppmov<0x118, 0xF>(v));   // row_shr:8
    v = fmaxf(v, dppmov<0x142, 0x2>(v));   // row_bcast:15 -> row1: lane31=max(0..31)
    v = fmaxf(v, dppmov<0x143, 0x4>(v));   // row_bcast:31 -> row2: lane47=max(0..47)
    return rdlane(v, 47);
}

// One SGA step (lane = d). Lanes >= 48 compute garbage that never propagates
// back into lanes 0..47.
__device__ __forceinline__ float sga_step(float A, float cs, float g0v, float g1v, float g2v,
                                          float g3v, float g4v, bool is47, bool first) {
    float dm1 = dppmov<0x138, 0xF>(A);             // wave_shr:1, lane0 keeps own
    float dp1 = dppmov<0x130, 0xF>(A);             // wave_shl:1
    dp1 = is47 ? A : dp1;                          // d+1 clamp at d=47
    float mx = wave_max48(A);
    float r = g0v * cs + g1v * A + g2v * dm1 + g3v * dp1 + g4v * mx;
    return first ? cs : r;
}

// ============================================================================
// W-pair kernel (round-6 design, WS=false instantiation): fwd scan (ga)
// stashes a0 fp16 on-chip (LDS tiles 0-7, static reg banks 8-11), rev scan
// (gb) combines, writes out = max(a0,a1) once. 1 wave/block, no barriers,
// 15.6 KB LDS -> 10 blocks/CU.
// ============================================================================
__global__ __launch_bounds__(64, 4) void sga_w4(const float* __restrict__ x,
                                                const float* __restrict__ ga,
                                                const float* __restrict__ gb,
                                                float* __restrict__ out) {
    __shared__ unsigned sstash[64][Dd];   // tiles 0..7, [t*8+r][lane]
    __shared__ float xo[Dd][TW + 1];      // x tile / flush tile

    const int bid = blockIdx.x;
    const int c = bid / Hh;
    const int h = bid - c * Hh;
    const int lane = threadIdx.x;
    const size_t HW = (size_t)Hh * Ww;

    const float* xrow = x + (size_t)c * Dd * HW + (size_t)h * Ww;
    const float* garow = ga + (size_t)c * 5 * HW + (size_t)h * Ww;
    const float* gbrow = gb + (size_t)c * 5 * HW + (size_t)h * Ww;
    float* orow = out + (size_t)c * Dd * HW + (size_t)h * Ww;

    const int dl = (lane < Dd) ? lane : (Dd - 1);
    const bool is47 = (lane == Dd - 1);

    int srow[3], scol[3];
#pragma unroll
    for (int i = 0; i < 3; ++i) {
        const int e4 = lane + i * 64;
        srow[i] = e4 >> 2;
        scol[i] = (e4 & 3) * 4;
    }
    const int gk = lane >> 4;
    const int gwi = lane & 15;

    float4 pre[3];
    float gA, g4r, gAn = 0.f, g4n = 0.f;
    unsigned tr[8];
    unsigned sv0[8], sv1[8], sv2[8], sv3[8];

    {
#pragma unroll
        for (int i = 0; i < 3; ++i)
            pre[i] = *reinterpret_cast<const float4*>(xrow + (size_t)srow[i] * HW + scol[i]);
        gA = garow[(size_t)gk * HW + gwi];
        g4r = garow[(size_t)4 * HW + gwi];
#pragma unroll
        for (int i = 0; i < 3; ++i) {
            xo[srow[i]][scol[i] + 0] = pre[i].x;
            xo[srow[i]][scol[i] + 1] = pre[i].y;
            xo[srow[i]][scol[i] + 2] = pre[i].z;
            xo[srow[i]][scol[i] + 3] = pre[i].w;
        }
    }

    float A = NEGBIG;

    // forward: a0 -> on-chip fp16 stash
    for (int t = 0; t < NT; ++t) {
        if (t + 1 < NT) {
            const int wn = (t + 1) * TW;
#pragma unroll
            for (int i = 0; i < 3; ++i)
                pre[i] = *reinterpret_cast<const float4*>(xrow + (size_t)srow[i] * HW + wn + scol[i]);
            gAn = garow[(size_t)gk * HW + wn + gwi];
            g4n = garow[(size_t)4 * HW + wn + gwi];
        }
#pragma unroll
        for (int wk = 0; wk < TW; ++wk) {
            const float g0v = rdlane(gA, wk);
            const float g1v = rdlane(gA, 16 + wk);
            const float g2v = rdlane(gA, 32 + wk);
            const float g3v = rdlane(gA, 48 + wk);
            const float g4v = rdlane(g4r, wk);
            const float cs = xo[dl][wk];
            A = sga_step(A, cs, g0v, g1v, g2v, g3v, g4v, is47, (t == 0 && wk == 0));
            const unsigned hu = f2h(A);
            if ((wk & 1) == 0) tr[wk >> 1] = hu;
            else tr[wk >> 1] |= hu << 16;
        }
        if (t < 8) {
            if (lane < Dd) {
#pragma unroll
                for (int r = 0; r < 8; ++r) sstash[t * 8 + r][lane] = tr[r];
            }
        } else if (t == 8) {
#pragma unroll
            for (int r = 0; r < 8; ++r) sv0[r] = tr[r];
        } else if (t == 9) {
#pragma unroll
            for (int r = 0; r < 8; ++r) sv1[r] = tr[r];
        } else if (t == 10) {
#pragma unroll
            for (int r = 0; r < 8; ++r) sv2[r] = tr[r];
        } else {
#pragma unroll
            for (int r = 0; r < 8; ++r) sv3[r] = tr[r];
        }
        if (t + 1 < NT) {
#pragma unroll
            for (int i = 0; i < 3; ++i) {
                xo[srow[i]][scol[i] + 0] = pre[i].x;
                xo[srow[i]][scol[i] + 1] = pre[i].y;
                xo[srow[i]][scol[i] + 2] = pre[i].z;
                xo[srow[i]][scol[i] + 3] = pre[i].w;
            }
            gA = gAn;
            g4r = g4n;
        }
    }

    // reverse + combine + single write
    A = NEGBIG;
    {
        const int w0 = (NT - 1) * TW;
        gA = gbrow[(size_t)gk * HW + w0 + gwi];
        g4r = gbrow[(size_t)4 * HW + w0 + gwi];
    }
    for (int t = NT - 1; t >= 0; --t) {
        const int w0 = t * TW;
        if (t > 0) {
            const int wn = w0 - TW;
#pragma unroll
            for (int i = 0; i < 3; ++i)
                pre[i] = *reinterpret_cast<const float4*>(xrow + (size_t)srow[i] * HW + wn + scol[i]);
            gAn = gbrow[(size_t)gk * HW + wn + gwi];
            g4n = gbrow[(size_t)4 * HW + wn + gwi];
        }
        unsigned rr[8];
        if (t < 8) {
#pragma unroll
            for (int r = 0; r < 8; ++r) rr[r] = sstash[t * 8 + r][dl];
        } else if (t == 8) {
#pragma unroll
            for (int r = 0; r < 8; ++r) rr[r] = sv0[r];
        } else if (t == 9) {
#pragma unroll
            for (int r = 0; r < 8; ++r) rr[r] = sv1[r];
        } else if (t == 10) {
#pragma unroll
            for (int r = 0; r < 8; ++r) rr[r] = sv2[r];
        } else {
#pragma unroll
            for (int r = 0; r < 8; ++r) rr[r] = sv3[r];
        }
#pragma unroll
        for (int wk = TW - 1; wk >= 0; --wk) {
            const float g0v = rdlane(gA, wk);
            const float g1v = rdlane(gA, 16 + wk);
            const float g2v = rdlane(gA, 32 + wk);
            const float g3v = rdlane(gA, 48 + wk);
            const float g4v = rdlane(g4r, wk);
            const float cs = xo[dl][wk];
            A = sga_step(A, cs, g0v, g1v, g2v, g3v, g4v, is47, (t == NT - 1 && wk == TW - 1));
            const unsigned u = rr[wk >> 1];
            const float a0 = h2f((unsigned short)((wk & 1) ? (u >> 16) : (u & 0xffffu)));
            if (lane < Dd) xo[lane][wk] = fmaxf(A, a0);
        }
#pragma unroll
        for (int i = 0; i < 3; ++i) {
            float4 v;
            v.x = xo[srow[i]][scol[i] + 0];
            v.y = xo[srow[i]][scol[i] + 1];
            v.z = xo[srow[i]][scol[i] + 2];
            v.w = xo[srow[i]][scol[i] + 3];
            *reinterpret_cast<float4*>(orow + (size_t)srow[i] * HW + w0 + scol[i]) = v;
        }
        if (t > 0) {
#pragma unroll
            for (int i = 0; i < 3; ++i) {
                xo[srow[i]][scol[i] + 0] = pre[i].x;
                xo[srow[i]][scol[i] + 1] = pre[i].y;
                xo[srow[i]][scol[i] + 2] = pre[i].z;
                xo[srow[i]][scol[i] + 3] = pre[i].w;
            }
            gA = gAn;
            g4r = g4n;
        }
    }
}

// ============================================================================
// H-pair kernel: round-5 sga_h3 VERBATIM (the proven ~105 µs variant).
// Block = 4 columns x 2 direction-waves = 8 waves (512 thr), 2 blocks/CU.
// KH2=4 (24 barriers). First 48 windows stash fp16; last 48 combine with the
// opposite chain's stash, RMW out once (fp32, coalesced 16B flushes with
// pipelined out-read prefetch): out = max(out, a2, a3).
// ============================================================================
constexpr int WT2 = 4;
constexpr int KH2 = 4;
constexpr int NP2 = Hh / KH2;     // 24 periods
constexpr int HALF = NP2 / 2;     // 12

__global__ __launch_bounds__(512, 4) void sga_h6(const float* __restrict__ x,
                                                 const float* __restrict__ gf,
                                                 const float* __restrict__ gr,
                                                 float* __restrict__ out) {
    __shared__ _Float16 stash[WT2][2][Hh / 2][Dd];   // 36864 B
    __shared__ float xs[2][2][KH2][Dd][WT2 + 1];     // 15360 B (pad 5: gcd(5,32)=1)
    __shared__ float osb[2][2][KH2][Dd][WT2 + 1];    // 15360 B
    __shared__ float gs[2][2][KH2][WT2][8];          // 4096 B (8-pad: aligned float4)
    // total 71680 B -> 2 blocks/CU

    // quad XCD swizzle: 4 sibling blocks covering one 64B line-span share bid%8.
    const int xcd = blockIdx.x & 7;
    const int within = blockIdx.x >> 3;          // 0..191
    const int L = xcd * 192 + within;
    const int quad = L >> 2, sub = L & 3;
    const int c = quad / 12;
    const int wq = quad % 12;
    const int w0 = wq * 16 + sub * 4;

    const int tid = threadIdx.x;
    const int lane = tid & 63;
    const int wv = tid >> 6;            // 0..7
    const int col = wv >> 1;            // 0..3
    const int dir = wv & 1;             // 0=fwd(h asc), 1=rev(h desc)
    const size_t HW = (size_t)Hh * Ww;

    const float* xb = x + (size_t)c * Dd * HW;
    const float* gfb = gf + (size_t)c * 5 * HW;
    const float* grb = gr + (size_t)c * 5 * HW;
    float* ob = out + (size_t)c * Dd * HW;

    const int dl = (lane < Dd) ? lane : (Dd - 1);
    const bool is47 = (lane == Dd - 1);

    // x / out staging decomposition: idx = tid + j*512 over [2cu][4hp][48d][4w]
    int w_[3], d_[3], hp_[3], cu_[3];
    size_t xoff_[3];
#pragma unroll
    for (int j = 0; j < 3; ++j) {
        const int idx = tid + j * 512;
        w_[j] = idx & 3;
        const int t = idx >> 2;
        d_[j] = t % Dd;
        const int t2 = t / Dd;
        hp_[j] = t2 & 3;
        cu_[j] = t2 >> 2;
        xoff_[j] = (size_t)d_[j] * HW + (w0 + w_[j]);
    }
    // g staging (tid < 160): [2cu][4hp][5k][4w], w fastest
    const int gw_ = tid & 3;
    const int gk_ = (tid >> 2) % 5;
    const int ghc = (tid >> 2) / 5;       // 0..7
    const int ghp_ = ghc & 3;
    const int gcu_ = ghc >> 2;
    const bool gst = tid < 160;

    auto hofs = [&](int cur, int P, int hp) -> int {
        const int p = P * KH2 + hp;
        return cur ? (Hh - 1 - p) : p;
    };

    float xr_[3], grg = 0.f, orr[2][3];

    // prologue: stage period 0 into buf 0
    {
#pragma unroll
        for (int j = 0; j < 3; ++j) xr_[j] = xb[xoff_[j] + (size_t)hofs(cu_[j], 0, hp_[j]) * Ww];
        if (gst) {
            const float* gp = gcu_ ? grb : gfb;
            grg = gp[(size_t)gk_ * HW + (size_t)hofs(gcu_, 0, ghp_) * Ww + (w0 + gw_)];
        }
#pragma unroll
        for (int j = 0; j < 3; ++j) xs[0][cu_[j]][hp_[j]][d_[j]][w_[j]] = xr_[j];
        if (gst) gs[0][gcu_][ghp_][gw_][gk_] = grg;
    }
    __syncthreads();

    float A = NEGBIG;

#pragma unroll 2
    for (int p = 0; p < NP2; ++p) {
        const int pb = p & 1;

        // (1) issue staging loads for period p+1
        if (p + 1 < NP2) {
#pragma unroll
            for (int j = 0; j < 3; ++j)
                xr_[j] = xb[xoff_[j] + (size_t)hofs(cu_[j], p + 1, hp_[j]) * Ww];
            if (gst) {
                const float* gp = gcu_ ? grb : gfb;
                grg = gp[(size_t)gk_ * HW + (size_t)hofs(gcu_, p + 1, ghp_) * Ww + (w0 + gw_)];
            }
        }
        // (2) issue out-reads for THIS period's osb (flushed next period)
        if (p >= HALF) {
#pragma unroll
            for (int j = 0; j < 3; ++j)
                orr[pb][j] = ob[xoff_[j] + (size_t)hofs(cu_[j], p, hp_[j]) * Ww];
        }

        // (3) compute KH2 windows
#pragma unroll
        for (int hp = 0; hp < KH2; ++hp) {
            const int q = p * KH2 + hp;
            const float cs = xs[pb][dir][hp][dl][col];
            const float* gbase = &gs[pb][dir][hp][col][0];
            const float4 g03 = *reinterpret_cast<const float4*>(gbase);
            const float g4 = gbase[4];
            A = sga_step(A, cs, g03.x, g03.y, g03.z, g03.w, g4, is47, q == 0);
            if (q < Hh / 2) {
                if (lane < Dd) stash[col][dir][q][lane] = (_Float16)A;
            } else {
                const float s = (float)stash[col][dir ^ 1][Hh - 1 - q][dl];
                const float o = fmaxf(A, s);
                if (lane < Dd) osb[pb][dir][hp][lane][col] = o;
            }
        }

        // (4) flush period p-1 osb, combined with out-reads issued at p-1
        if (p > HALF) {
#pragma unroll
            for (int j = 0; j < 3; ++j) {
                const float v = fmaxf(osb[pb ^ 1][cu_[j]][hp_[j]][d_[j]][w_[j]], orr[pb ^ 1][j]);
                ob[xoff_[j] + (size_t)hofs(cu_[j], p - 1, hp_[j]) * Ww] = v;
            }
        }

        // (5) commit staged regs for p+1
        if (p + 1 < NP2) {
#pragma unroll
            for (int j = 0; j < 3; ++j) xs[pb ^ 1][cu_[j]][hp_[j]][d_[j]][w_[j]] = xr_[j];
            if (gst) gs[pb ^ 1][gcu_][ghp_][gw_][gk_] = grg;
        }
        __syncthreads();
    }

    // epilogue: flush last period (p = NP2-1, pb = 1)
    {
#pragma unroll
        for (int j = 0; j < 3; ++j) {
            const float v = fmaxf(osb[1][cu_[j]][hp_[j]][d_[j]][w_[j]], orr[1][j]);
            ob[xoff_[j] + (size_t)hofs(cu_[j], NP2 - 1, hp_[j]) * Ww] = v;
        }
    }
}

extern "C" void kernel_launch(void* const* d_in, const int* in_sizes, int n_in,
                              void* d_out, int out_size, void* d_ws, size_t ws_size,
                              hipStream_t stream) {
    const float* x  = (const float*)d_in[0];
    const float* g0 = (const float*)d_in[1];
    const float* g1 = (const float*)d_in[2];
    const float* g2 = (const float*)d_in[3];
    const float* g3 = (const float*)d_in[4];
    float* out = (float*)d_out;

    // W pair: out = max(a0, a1)        (fwd stashes a0 on-chip, rev combines)
    sga_w4<<<Cc * Hh, 64, 0, stream>>>(x, g0, g1, out);
    // H pair: out = max(out, a2, a3)   (single fp32 RMW, coalesced flushes)
    sga_h6<<<Cc * (Ww / 16) * 4, 512, 0, stream>>>(x, g2, g3, out);
}

// Round 10
// 272.501 us; speedup vs baseline: 1.0545x; 1.0545x over previous
//
#include <hip/hip_runtime.h>

// Problem constants (B=1)
constexpr int Cc = 32;
constexpr int Dd = 48;
constexpr int Hh = 96;
constexpr int Ww = 192;
constexpr int TW = 16;           // W-kernel tile width
constexpr int NT = Ww / TW;      // 12 tiles
constexpr float NEGBIG = -3.402823466e+38f;

// ---- DPP helpers ------------------------------------------------------------
// NOTE: must use __builtin_amdgcn_update_dpp (not inline asm) — the compiler's
// hazard recognizer inserts the required VALU->DPP wait states only for
// compiler-known DPP ops. Inline-asm DPP caused silent corruption (round 3).
template <int CTRL, int RM>
__device__ __forceinline__ float dppmov(float v) {
    int i = __builtin_bit_cast(int, v);
    int r = __builtin_amdgcn_update_dpp(i, i, CTRL, RM, 0xF, false);
    return __builtin_bit_cast(float, r);
}

__device__ __forceinline__ float rdlane(float v, int idx) {
    int r = __builtin_amdgcn_readlane(__builtin_bit_cast(int, v), idx);
    return __builtin_bit_cast(float, r);
}

__device__ __forceinline__ unsigned f2h(float v) {
    return (unsigned)__builtin_bit_cast(unsigned short, (_Float16)v);
}
__device__ __forceinline__ float h2f(unsigned short u) {
    return (float)__builtin_bit_cast(_Float16, u);
}

// Max over lanes 0..47, broadcast. Row-confined: junk in lanes 48..63 never
// enters the reduction.
__device__ __forceinline__ float wave_max48(float v) {
    v = fmaxf(v, dppmov<0x111, 0xF>(v));   // row_shr:1
    v = fmaxf(v, dppmov<0x112, 0xF>(v));   // row_shr:2
    v = fmaxf(v, dppmov<0x114, 0xF>(v));   // row_shr:4
    v = fmaxf(v, dppmov<0x118, 0xF>(v));   // row_shr:8
    v = fmaxf(v, dppmov<0x142, 0x2>(v));   // row_bcast:15 -> row1: lane31=max(0..31)
    v = fmaxf(v, dppmov<0x143, 0x4>(v));   // row_bcast:31 -> row2: lane47=max(0..47)
    return rdlane(v, 47);
}

// One SGA step (lane = d). Lanes >= 48 compute garbage that never propagates
// back into lanes 0..47.
__device__ __forceinline__ float sga_step(float A, float cs, float g0v, float g1v, float g2v,
                                          float g3v, float g4v, bool is47, bool first) {
    float dm1 = dppmov<0x138, 0xF>(A);             // wave_shr:1, lane0 keeps own
    float dp1 = dppmov<0x130, 0xF>(A);             // wave_shl:1
    dp1 = is47 ? A : dp1;                          // d+1 clamp at d=47
    float mx = wave_max48(A);
    float r = g0v * cs + g1v * A + g2v * dm1 + g3v * dp1 + g4v * mx;
    return first ? cs : r;
}

// ============================================================================
// W-pair kernel (proven, rounds 6-9, ~94-106 us): fwd scan (ga) stashes a0
// fp16 on-chip (LDS tiles 0-7, static reg banks 8-11), rev scan (gb)
// combines, writes out = max(a0,a1) once. 1 wave/block, no barriers,
// 15.6 KB LDS -> ~10 blocks/CU.
// ============================================================================
__global__ __launch_bounds__(64, 4) void sga_w4(const float* __restrict__ x,
                                                const float* __restrict__ ga,
                                                const float* __restrict__ gb,
                                                float* __restrict__ out) {
    __shared__ unsigned sstash[64][Dd];   // tiles 0..7, [t*8+r][lane]
    __shared__ float xo[Dd][TW + 1];      // x tile / flush tile

    const int bid = blockIdx.x;
    const int c = bid / Hh;
    const int h = bid - c * Hh;
    const int lane = threadIdx.x;
    const size_t HW = (size_t)Hh * Ww;

    const float* xrow = x + (size_t)c * Dd * HW + (size_t)h * Ww;
    const float* garow = ga + (size_t)c * 5 * HW + (size_t)h * Ww;
    const float* gbrow = gb + (size_t)c * 5 * HW + (size_t)h * Ww;
    float* orow = out + (size_t)c * Dd * HW + (size_t)h * Ww;

    const int dl = (lane < Dd) ? lane : (Dd - 1);
    const bool is47 = (lane == Dd - 1);

    int srow[3], scol[3];
#pragma unroll
    for (int i = 0; i < 3; ++i) {
        const int e4 = lane + i * 64;
        srow[i] = e4 >> 2;
        scol[i] = (e4 & 3) * 4;
    }
    const int gk = lane >> 4;
    const int gwi = lane & 15;

    float4 pre[3];
    float gA, g4r, gAn = 0.f, g4n = 0.f;
    unsigned tr[8];
    unsigned sv0[8], sv1[8], sv2[8], sv3[8];

    {
#pragma unroll
        for (int i = 0; i < 3; ++i)
            pre[i] = *reinterpret_cast<const float4*>(xrow + (size_t)srow[i] * HW + scol[i]);
        gA = garow[(size_t)gk * HW + gwi];
        g4r = garow[(size_t)4 * HW + gwi];
#pragma unroll
        for (int i = 0; i < 3; ++i) {
            xo[srow[i]][scol[i] + 0] = pre[i].x;
            xo[srow[i]][scol[i] + 1] = pre[i].y;
            xo[srow[i]][scol[i] + 2] = pre[i].z;
            xo[srow[i]][scol[i] + 3] = pre[i].w;
        }
    }

    float A = NEGBIG;

    // forward: a0 -> on-chip fp16 stash
    for (int t = 0; t < NT; ++t) {
        if (t + 1 < NT) {
            const int wn = (t + 1) * TW;
#pragma unroll
            for (int i = 0; i < 3; ++i)
                pre[i] = *reinterpret_cast<const float4*>(xrow + (size_t)srow[i] * HW + wn + scol[i]);
            gAn = garow[(size_t)gk * HW + wn + gwi];
            g4n = garow[(size_t)4 * HW + wn + gwi];
        }
#pragma unroll
        for (int wk = 0; wk < TW; ++wk) {
            const float g0v = rdlane(gA, wk);
            const float g1v = rdlane(gA, 16 + wk);
            const float g2v = rdlane(gA, 32 + wk);
            const float g3v = rdlane(gA, 48 + wk);
            const float g4v = rdlane(g4r, wk);
            const float cs = xo[dl][wk];
            A = sga_step(A, cs, g0v, g1v, g2v, g3v, g4v, is47, (t == 0 && wk == 0));
            const unsigned hu = f2h(A);
            if ((wk & 1) == 0) tr[wk >> 1] = hu;
            else tr[wk >> 1] |= hu << 16;
        }
        if (t < 8) {
            if (lane < Dd) {
#pragma unroll
                for (int r = 0; r < 8; ++r) sstash[t * 8 + r][lane] = tr[r];
            }
        } else if (t == 8) {
#pragma unroll
            for (int r = 0; r < 8; ++r) sv0[r] = tr[r];
        } else if (t == 9) {
#pragma unroll
            for (int r = 0; r < 8; ++r) sv1[r] = tr[r];
        } else if (t == 10) {
#pragma unroll
            for (int r = 0; r < 8; ++r) sv2[r] = tr[r];
        } else {
#pragma unroll
            for (int r = 0; r < 8; ++r) sv3[r] = tr[r];
        }
        if (t + 1 < NT) {
#pragma unroll
            for (int i = 0; i < 3; ++i) {
                xo[srow[i]][scol[i] + 0] = pre[i].x;
                xo[srow[i]][scol[i] + 1] = pre[i].y;
                xo[srow[i]][scol[i] + 2] = pre[i].z;
                xo[srow[i]][scol[i] + 3] = pre[i].w;
            }
            gA = gAn;
            g4r = g4n;
        }
    }

    // reverse + combine + single write
    A = NEGBIG;
    {
        const int w0 = (NT - 1) * TW;
        gA = gbrow[(size_t)gk * HW + w0 + gwi];
        g4r = gbrow[(size_t)4 * HW + w0 + gwi];
    }
    for (int t = NT - 1; t >= 0; --t) {
        const int w0 = t * TW;
        if (t > 0) {
            const int wn = w0 - TW;
#pragma unroll
            for (int i = 0; i < 3; ++i)
                pre[i] = *reinterpret_cast<const float4*>(xrow + (size_t)srow[i] * HW + wn + scol[i]);
            gAn = gbrow[(size_t)gk * HW + wn + gwi];
            g4n = gbrow[(size_t)4 * HW + wn + gwi];
        }
        unsigned rr[8];
        if (t < 8) {
#pragma unroll
            for (int r = 0; r < 8; ++r) rr[r] = sstash[t * 8 + r][dl];
        } else if (t == 8) {
#pragma unroll
            for (int r = 0; r < 8; ++r) rr[r] = sv0[r];
        } else if (t == 9) {
#pragma unroll
            for (int r = 0; r < 8; ++r) rr[r] = sv1[r];
        } else if (t == 10) {
#pragma unroll
            for (int r = 0; r < 8; ++r) rr[r] = sv2[r];
        } else {
#pragma unroll
            for (int r = 0; r < 8; ++r) rr[r] = sv3[r];
        }
#pragma unroll
        for (int wk = TW - 1; wk >= 0; --wk) {
            const float g0v = rdlane(gA, wk);
            const float g1v = rdlane(gA, 16 + wk);
            const float g2v = rdlane(gA, 32 + wk);
            const float g3v = rdlane(gA, 48 + wk);
            const float g4v = rdlane(g4r, wk);
            const float cs = xo[dl][wk];
            A = sga_step(A, cs, g0v, g1v, g2v, g3v, g4v, is47, (t == NT - 1 && wk == TW - 1));
            const unsigned u = rr[wk >> 1];
            const float a0 = h2f((unsigned short)((wk & 1) ? (u >> 16) : (u & 0xffffu)));
            if (lane < Dd) xo[lane][wk] = fmaxf(A, a0);
        }
#pragma unroll
        for (int i = 0; i < 3; ++i) {
            float4 v;
            v.x = xo[srow[i]][scol[i] + 0];
            v.y = xo[srow[i]][scol[i] + 1];
            v.z = xo[srow[i]][scol[i] + 2];
            v.w = xo[srow[i]][scol[i] + 3];
            *reinterpret_cast<float4*>(orow + (size_t)srow[i] * HW + w0 + scol[i]) = v;
        }
        if (t > 0) {
#pragma unroll
            for (int i = 0; i < 3; ++i) {
                xo[srow[i]][scol[i] + 0] = pre[i].x;
                xo[srow[i]][scol[i] + 1] = pre[i].y;
                xo[srow[i]][scol[i] + 2] = pre[i].z;
                xo[srow[i]][scol[i] + 3] = pre[i].w;
            }
            gA = gAn;
            g4r = g4n;
        }
    }
}

// ============================================================================
// H-pair kernel sga_h7 = round-4 sga_h2 VERBATIM (measured ~114 us for BOTH
// directions). Block = 8 columns x 2 direction-waves = 16 waves (1024 thr),
// 1 block/CU (134 KB LDS). KH=4 (24 barriers). First 48 windows stash fp16;
// last 48 combine with the opposite chain's stash, single fp32 RMW of out
// with 32B-sector-aligned stores: out = max(out, a2, a3).
// ============================================================================
constexpr int HWT = 8;
constexpr int HKH = 4;
constexpr int HNP = Hh / HKH;     // 24 periods
constexpr int HHALF = HNP / 2;    // 12

__global__ __launch_bounds__(1024) void sga_h7(const float* __restrict__ x,
                                               const float* __restrict__ gf,
                                               const float* __restrict__ gr,
                                               float* __restrict__ out) {
    __shared__ _Float16 stash[HWT][2][Hh / 2][Dd];   // 73728 B
    __shared__ float xs[2][2][HKH][Dd][9];           // 27648 B  (pad 9: conflict-free)
    __shared__ float osb[2][2][HKH][Dd][9];          // 27648 B
    __shared__ float gs[2][2][HKH][HWT][8];          // 8192 B   (8-pad: aligned float4)

    // XCD pair-swizzle: blocks covering the two 32B halves of each 64B line
    // (adjacent wt pairs) are 8 apart in blockIdx -> same XCD. Grid = 768.
    const int xcd = blockIdx.x & 7;
    const int within = blockIdx.x >> 3;          // 0..95
    const int pairid = xcd * 48 + (within >> 1); // 0..383
    const int sub = within & 1;
    const int c = pairid / 12;
    const int w0 = ((pairid % 12) * 2 + sub) * HWT;

    const int tid = threadIdx.x;
    const int lane = tid & 63;
    const int wv = tid >> 6;            // 0..15
    const int col = wv >> 1;            // 0..7
    const int dir = wv & 1;             // 0=fwd(h asc), 1=rev(h desc)
    const size_t HW = (size_t)Hh * Ww;

    const float* xb = x + (size_t)c * Dd * HW;
    const float* gfb = gf + (size_t)c * 5 * HW;
    const float* grb = gr + (size_t)c * 5 * HW;
    float* ob = out + (size_t)c * Dd * HW;

    const int dl = (lane < Dd) ? lane : (Dd - 1);
    const bool is47 = (lane == Dd - 1);

    // x / out staging decomposition: idx = tid + j*1024 over [2][HKH][Dd][HWT]
    int w_[3], d_[3], hp_[3], cu_[3];
    size_t xoff_[3];
#pragma unroll
    for (int j = 0; j < 3; ++j) {
        const int idx = tid + j * 1024;
        w_[j] = idx & 7;
        const int t = idx >> 3;
        d_[j] = t % Dd;
        const int t2 = t / Dd;
        hp_[j] = t2 & 3;
        cu_[j] = t2 >> 2;
        xoff_[j] = (size_t)d_[j] * HW + (w0 + w_[j]);
    }
    // g staging (tid < 320): idx over [2][HKH][5][HWT], w fastest (coalesced)
    const int gw_ = tid & 7;
    const int gk_ = (tid >> 3) % 5;
    const int ghc = (tid >> 3) / 5;       // 0..7
    const int ghp_ = ghc & 3;
    const int gcu_ = ghc >> 2;
    const bool gst = tid < 320;

    auto hofs = [&](int cur, int P, int hp) -> int {
        const int p = P * HKH + hp;
        return cur ? (Hh - 1 - p) : p;
    };

    float xr_[3], grg = 0.f, orr[2][3];

    // prologue: stage period 0 into buf 0
    {
#pragma unroll
        for (int j = 0; j < 3; ++j) xr_[j] = xb[xoff_[j] + (size_t)hofs(cu_[j], 0, hp_[j]) * Ww];
        if (gst) {
            const float* gp = gcu_ ? grb : gfb;
            grg = gp[(size_t)gk_ * HW + (size_t)hofs(gcu_, 0, ghp_) * Ww + (w0 + gw_)];
        }
#pragma unroll
        for (int j = 0; j < 3; ++j) xs[0][cu_[j]][hp_[j]][d_[j]][w_[j]] = xr_[j];
        if (gst) gs[0][gcu_][ghp_][gw_][gk_] = grg;
    }
    __syncthreads();

    float A = NEGBIG;

#pragma unroll 2
    for (int p = 0; p < HNP; ++p) {
        const int pb = p & 1;

        // (1) issue staging loads for period p+1
        if (p + 1 < HNP) {
#pragma unroll
            for (int j = 0; j < 3; ++j)
                xr_[j] = xb[xoff_[j] + (size_t)hofs(cu_[j], p + 1, hp_[j]) * Ww];
            if (gst) {
                const float* gp = gcu_ ? grb : gfb;
                grg = gp[(size_t)gk_ * HW + (size_t)hofs(gcu_, p + 1, ghp_) * Ww + (w0 + gw_)];
            }
        }
        // (2) issue out-reads for THIS period's osb (flushed next period)
        if (p >= HHALF) {
#pragma unroll
            for (int j = 0; j < 3; ++j)
                orr[pb][j] = ob[xoff_[j] + (size_t)hofs(cu_[j], p, hp_[j]) * Ww];
        }

        // (3) compute HKH windows
#pragma unroll
        for (int hp = 0; hp < HKH; ++hp) {
            const int q = p * HKH + hp;
            const float cs = xs[pb][dir][hp][dl][col];
            const float* gbase = &gs[pb][dir][hp][col][0];
            const float4 g03 = *reinterpret_cast<const float4*>(gbase);
            const float g4 = gbase[4];
            A = sga_step(A, cs, g03.x, g03.y, g03.z, g03.w, g4, is47, q == 0);
            if (q < Hh / 2) {
                if (lane < Dd) stash[col][dir][q][lane] = (_Float16)A;
            } else {
                const float s = (float)stash[col][dir ^ 1][Hh - 1 - q][dl];
                const float o = fmaxf(A, s);
                if (lane < Dd) osb[pb][dir][hp][lane][col] = o;
            }
        }

        // (4) flush period p-1 osb, combined with out-reads issued at p-1
        if (p > HHALF) {
#pragma unroll
            for (int j = 0; j < 3; ++j) {
                const float v = fmaxf(osb[pb ^ 1][cu_[j]][hp_[j]][d_[j]][w_[j]], orr[pb ^ 1][j]);
                ob[xoff_[j] + (size_t)hofs(cu_[j], p - 1, hp_[j]) * Ww] = v;
            }
        }

        // (5) commit staged regs for p+1
        if (p + 1 < HNP) {
#pragma unroll
            for (int j = 0; j < 3; ++j) xs[pb ^ 1][cu_[j]][hp_[j]][d_[j]][w_[j]] = xr_[j];
            if (gst) gs[pb ^ 1][gcu_][ghp_][gw_][gk_] = grg;
        }
        __syncthreads();
    }

    // epilogue: flush last period (p = HNP-1, pb = 1)
    {
#pragma unroll
        for (int j = 0; j < 3; ++j) {
            const float v = fmaxf(osb[1][cu_[j]][hp_[j]][d_[j]][w_[j]], orr[1][j]);
            ob[xoff_[j] + (size_t)hofs(cu_[j], HNP - 1, hp_[j]) * Ww] = v;
        }
    }
}

extern "C" void kernel_launch(void* const* d_in, const int* in_sizes, int n_in,
                              void* d_out, int out_size, void* d_ws, size_t ws_size,
                              hipStream_t stream) {
    const float* x  = (const float*)d_in[0];
    const float* g0 = (const float*)d_in[1];
    const float* g1 = (const float*)d_in[2];
    const float* g2 = (const float*)d_in[3];
    const float* g3 = (const float*)d_in[4];
    float* out = (float*)d_out;

    // W pair: out = max(a0, a1)        (fwd stashes a0 on-chip, rev combines)
    sga_w4<<<Cc * Hh, 64, 0, stream>>>(x, g0, g1, out);
    // H pair: out = max(out, a2, a3)   (fused both-dir, single fp32 RMW)
    sga_h7<<<Cc * (Ww / HWT), 1024, 0, stream>>>(x, g2, g3, out);
}